// Round 3
// baseline (53.847 us; speedup 1.0000x reference)
//
#include <hip/hip_runtime.h>

constexpr int NJ = 31;
constexpr int RPB = 64;  // one wave per block, one batch row per lane

struct M34 {
    float r[9];  // row-major 3x3
    float t[3];
};

// ---- LDS tiles (per block) ----
// sq : 64 rows x 16 f4-slots (16384 B). Slot s of row r holds f4 element (s ^ (r&15))
//      of the current pass's 16-f4 range. Written linearly by global_load_lds with
//      inverse-swizzled GLOBAL source; read/overwritten with the swizzled index.
// sf : 64 rows x 16 dword-slots (4096 B), same slot-XOR scheme for fbl scalars.
// soff: offsets, 31x16 floats (1984 B), broadcast reads.

__device__ __forceinline__ float4 ldq(const float* sq, int r, int j) {
    return *reinterpret_cast<const float4*>(&sq[r * 64 + (j ^ (r & 15)) * 4]);
}
__device__ __forceinline__ void stq(float* sq, int r, int j, float4 v) {
    *reinterpret_cast<float4*>(&sq[r * 64 + (j ^ (r & 15)) * 4]) = v;
}
__device__ __forceinline__ float ldf(const float* sf, int r, int j) {
    return sf[r * 16 + (j ^ (r & 15))];
}

// RT_j = R4(q) @ T_j as 3x4 affine; T_j = offsets[j], translation scaled by len.
__device__ __forceinline__ void make_RT(int j, float4 q, float len,
                                        const float* __restrict__ soff,
                                        float Rr[9], float Rt[3]) {
    const float w = q.x, x = q.y, y = q.z, z = q.w;
    const float two_s = 2.0f / (w * w + x * x + y * y + z * z);
    float R[9];
    R[0] = 1.0f - two_s * (y * y + z * z);
    R[1] = two_s * (x * y - z * w);
    R[2] = two_s * (x * z + y * w);
    R[3] = two_s * (x * y + z * w);
    R[4] = 1.0f - two_s * (x * x + z * z);
    R[5] = two_s * (y * z - x * w);
    R[6] = two_s * (x * z - y * w);
    R[7] = two_s * (y * z + x * w);
    R[8] = 1.0f - two_s * (x * x + y * y);

    const float* O = soff + j * 16;  // uniform broadcast reads
    const float ot0 = O[3] * len, ot1 = O[7] * len, ot2 = O[11] * len;
#pragma unroll
    for (int r = 0; r < 3; ++r) {
#pragma unroll
        for (int c = 0; c < 3; ++c) {
            Rr[r * 3 + c] = R[r * 3 + 0] * O[0 * 4 + c] +
                            R[r * 3 + 1] * O[1 * 4 + c] +
                            R[r * 3 + 2] * O[2 * 4 + c];
        }
        Rt[r] = R[r * 3 + 0] * ot0 + R[r * 3 + 1] * ot1 + R[r * 3 + 2] * ot2;
    }
}

// child = parent ∘ RT_j; writes (t,1) into the tile at pass-local slot p.
__device__ __forceinline__ M34 step(const M34& P, int jg, int p,
                                    float* __restrict__ sq,
                                    const float* __restrict__ sf,
                                    const float* __restrict__ soff, int lane) {
    float4 q = ldq(sq, lane, p);
    float Rr[9], Rt[3];
    make_RT(jg, q, ldf(sf, lane, p), soff, Rr, Rt);
    M34 C;
#pragma unroll
    for (int r = 0; r < 3; ++r) {
#pragma unroll
        for (int c = 0; c < 3; ++c) {
            C.r[r * 3 + c] = P.r[r * 3 + 0] * Rr[0 * 3 + c] +
                             P.r[r * 3 + 1] * Rr[1 * 3 + c] +
                             P.r[r * 3 + 2] * Rr[2 * 3 + c];
        }
        C.t[r] = P.r[r * 3 + 0] * Rt[0] + P.r[r * 3 + 1] * Rt[1] +
                 P.r[r * 3 + 2] * Rt[2] + P.t[r];
    }
    stq(sq, lane, p, make_float4(C.t[0], C.t[1], C.t[2], 1.0f));
    return C;
}

// Stage one pass's quat range: 16 f4 per row (nf4 real, rest padded w/ dup loads).
__device__ __forceinline__ void stage_quat(const float* __restrict__ joint,
                                           float* __restrict__ sq, int rowBase,
                                           int f0, int nf4, int lane) {
#pragma unroll
    for (int k = 0; k < 16; ++k) {
        const int row = k * 4 + (lane >> 4);
        const int s = lane & 15;
        int q = s ^ (row & 15);
        if (q >= nf4) q = 0;  // pad slot: harmless duplicate, never read
        const float* g = joint + (size_t)(rowBase + row) * (NJ * 4) + f0 + q * 4;
        __builtin_amdgcn_global_load_lds(
            (const __attribute__((address_space(1))) unsigned int*)g,
            (__attribute__((address_space(3))) unsigned int*)(sq + k * 256), 16, 0, 0);
    }
}

// Stage one pass's fbl range: 16 scalars per row (nf real).
__device__ __forceinline__ void stage_fbl(const float* __restrict__ fbl,
                                          float* __restrict__ sf, int rowBase,
                                          int j0, int nf, int lane) {
#pragma unroll
    for (int k = 0; k < 16; ++k) {
        const int row = k * 4 + (lane >> 4);
        const int s = lane & 15;
        int q = s ^ (row & 15);
        if (q >= nf) q = 0;
        const float* g = fbl + (size_t)(rowBase + row) * NJ + j0 + q;
        __builtin_amdgcn_global_load_lds(
            (const __attribute__((address_space(1))) unsigned int*)g,
            (__attribute__((address_space(3))) unsigned int*)(sf + k * 64), 4, 0, 0);
    }
}

// Coalesced store of one pass's outputs: nf4 real f4 per row at out-float f0.
__device__ __forceinline__ void store_pass(float* __restrict__ out,
                                           const float* __restrict__ sq, int rowBase,
                                           int f0, int nf4, int lane) {
#pragma unroll
    for (int k = 0; k < 16; ++k) {
        const int row = k * 4 + (lane >> 4);
        const int s = lane & 15;
        if (s < nf4) {
            float4 v = ldq(sq, row, s);  // out f4 index s of row
            *reinterpret_cast<float4*>(out + (size_t)(rowBase + row) * (NJ * 4) + f0 + s * 4) = v;
        }
    }
}

__global__ __launch_bounds__(RPB) void fk_layer_kernel(
    const float* __restrict__ root_position,  // (B,3)
    const float* __restrict__ joint,          // (B, NJ*4)
    const float* __restrict__ fbl,            // (B, NJ)
    const float* __restrict__ offsets,        // (NJ,4,4)
    float* __restrict__ out) {                // (B, NJ, 4)
    __shared__ float sq[RPB * 64];    // 16384 B
    __shared__ float sf[RPB * 16];    // 4096 B
    __shared__ float soff[NJ * 16];   // 1984 B

    const int lane = threadIdx.x;
    const int rowBase = blockIdx.x * RPB;

    for (int i = lane; i < NJ * 16; i += RPB) soff[i] = offsets[i];

    // ---- pass 1: joints 0..15 (floats [0,64) of each row) ----
    stage_quat(joint, sq, rowBase, 0, 16, lane);
    stage_fbl(fbl, sf, rowBase, 0, 16, lane);
    __syncthreads();  // drains vmcnt before LDS reads

    const size_t b = (size_t)(rowBase + lane);
    const float rx = root_position[b * 3 + 0] * 100.0f;
    const float ry = root_position[b * 3 + 1] * 100.0f;
    const float rz = root_position[b * 3 + 2] * 100.0f;

    M34 M0;
    {
        float4 q = ldq(sq, lane, 0);
        float Rr[9], Rt[3];
        make_RT(0, q, ldf(sf, lane, 0), soff, Rr, Rt);
#pragma unroll
        for (int i = 0; i < 9; ++i) M0.r[i] = Rr[i];
        M0.t[0] = Rt[0] + rx;
        M0.t[1] = Rt[1] + ry;
        M0.t[2] = Rt[2] + rz;
        stq(sq, lane, 0, make_float4(M0.t[0], M0.t[1], M0.t[2], 1.0f));
    }

    M34 cur = M0;
#pragma unroll
    for (int j = 1; j <= 5; ++j) cur = step(cur, j, j, sq, sf, soff, lane);
    cur = M0;
#pragma unroll
    for (int j = 6; j <= 10; ++j) cur = step(cur, j, j, sq, sf, soff, lane);
    cur = M0;
    M34 M13;
#pragma unroll
    for (int j = 11; j <= 15; ++j) {
        cur = step(cur, j, j, sq, sf, soff, lane);
        if (j == 13) M13 = cur;
    }

    __syncthreads();  // compute done (LDS writes visible; 1-wave: cheap)
    store_pass(out, sq, rowBase, 0, 16, lane);
    __syncthreads();  // drain ds_reads of stores before DMA overwrites the tile

    // ---- pass 2: joints 16..30 (floats [64,124) of each row) ----
    stage_quat(joint, sq, rowBase, 64, 15, lane);
    stage_fbl(fbl, sf, rowBase, 16, 15, lane);
    __syncthreads();  // drains vmcnt

    cur = M13;
#pragma unroll
    for (int j = 16; j <= 20; ++j) cur = step(cur, j, j - 16, sq, sf, soff, lane);
    cur = M13;
#pragma unroll
    for (int j = 21; j <= 25; ++j) cur = step(cur, j, j - 16, sq, sf, soff, lane);
    cur = M13;
#pragma unroll
    for (int j = 26; j <= 30; ++j) cur = step(cur, j, j - 16, sq, sf, soff, lane);

    __syncthreads();
    store_pass(out, sq, rowBase, 64, 15, lane);
}

extern "C" void kernel_launch(void* const* d_in, const int* in_sizes, int n_in,
                              void* d_out, int out_size, void* d_ws, size_t ws_size,
                              hipStream_t stream) {
    const float* root = (const float*)d_in[0];
    const float* joint = (const float*)d_in[1];
    const float* fblp = (const float*)d_in[2];
    const float* offs = (const float*)d_in[3];
    float* out = (float*)d_out;

    const int B = in_sizes[0] / 3;  // 131072, multiple of RPB
    fk_layer_kernel<<<B / RPB, RPB, 0, stream>>>(root, joint, fblp, offs, out);
}

// Round 4
// 46.116 us; speedup vs baseline: 1.1676x; 1.1676x over previous
//
#include <hip/hip_runtime.h>

constexpr int NJ = 31;
constexpr int RPB = 64;       // one wave per block, one batch row per lane
constexpr int JF = NJ * 4;    // 124 floats per joint/out row

struct M34 {
    float r[9];  // row-major 3x3
    float t[3];
};

// RT_j = R4(q) @ T_j as 3x4 affine; T_j = offsets[j], translation scaled by len.
__device__ __forceinline__ void make_RT(int j, float4 q, float len,
                                        const float* __restrict__ soff,
                                        float Rr[9], float Rt[3]) {
    const float w = q.x, x = q.y, y = q.z, z = q.w;
    const float two_s = 2.0f / (w * w + x * x + y * y + z * z);
    float R[9];
    R[0] = 1.0f - two_s * (y * y + z * z);
    R[1] = two_s * (x * y - z * w);
    R[2] = two_s * (x * z + y * w);
    R[3] = two_s * (x * y + z * w);
    R[4] = 1.0f - two_s * (x * x + z * z);
    R[5] = two_s * (y * z - x * w);
    R[6] = two_s * (x * z - y * w);
    R[7] = two_s * (y * z + x * w);
    R[8] = 1.0f - two_s * (x * x + y * y);

    const float* O = soff + j * 16;  // LDS, lane-uniform broadcast reads
    const float ot0 = O[3] * len, ot1 = O[7] * len, ot2 = O[11] * len;
#pragma unroll
    for (int r = 0; r < 3; ++r) {
#pragma unroll
        for (int c = 0; c < 3; ++c) {
            Rr[r * 3 + c] = R[r * 3 + 0] * O[0 * 4 + c] +
                            R[r * 3 + 1] * O[1 * 4 + c] +
                            R[r * 3 + 2] * O[2 * 4 + c];
        }
        Rt[r] = R[r * 3 + 0] * ot0 + R[r * 3 + 1] * ot1 + R[r * 3 + 2] * ot2;
    }
}

// child = parent ∘ RT_j; writes (t,1) back into srow (overwrites quat j).
__device__ __forceinline__ M34 step(const M34& P, int j,
                                    float* __restrict__ srow,
                                    const float* __restrict__ fb,  // registers
                                    const float* __restrict__ soff) {
    float4 q = *reinterpret_cast<const float4*>(&srow[j * 4]);
    float Rr[9], Rt[3];
    make_RT(j, q, fb[j], soff, Rr, Rt);
    M34 C;
#pragma unroll
    for (int r = 0; r < 3; ++r) {
#pragma unroll
        for (int c = 0; c < 3; ++c) {
            C.r[r * 3 + c] = P.r[r * 3 + 0] * Rr[0 * 3 + c] +
                             P.r[r * 3 + 1] * Rr[1 * 3 + c] +
                             P.r[r * 3 + 2] * Rr[2 * 3 + c];
        }
        C.t[r] = P.r[r * 3 + 0] * Rt[0] + P.r[r * 3 + 1] * Rt[1] +
                 P.r[r * 3 + 2] * Rt[2] + P.t[r];
    }
    *reinterpret_cast<float4*>(&srow[j * 4]) = make_float4(C.t[0], C.t[1], C.t[2], 1.0f);
    return C;
}

__global__ __launch_bounds__(RPB) void fk_layer_kernel(
    const float* __restrict__ root_position,  // (B,3)
    const float* __restrict__ joint,          // (B, NJ*4)
    const float* __restrict__ fbl,            // (B, NJ)
    const float* __restrict__ offsets,        // (NJ,4,4)
    float* __restrict__ out) {                // (B, NJ, 4)
    __shared__ float sq[RPB * JF];    // 31744 B: quats in, outputs overwrite in place
    __shared__ float soff[NJ * 16];   // 1984 B

    const int lane = threadIdx.x;
    const int rowBase = blockIdx.x * RPB;
    const size_t b = (size_t)(rowBase + lane);

    // offsets -> LDS (tiny, broadcast-read later)
    for (int i = lane; i < NJ * 16; i += RPB) soff[i] = offsets[i];

    // quat tile -> LDS: 31 linear 1KB chunks, async direct-to-LDS, width=16
    {
        const float* gbase = joint + (size_t)rowBase * JF;
#pragma unroll
        for (int c = 0; c < NJ; ++c) {
            const float* g = gbase + c * 256 + lane * 4;  // contiguous per chunk
            float* l = sq + c * 256;                      // wave-uniform base
            __builtin_amdgcn_global_load_lds(
                (const __attribute__((address_space(1))) unsigned int*)g,
                (__attribute__((address_space(3))) unsigned int*)l, 16, 0, 0);
        }
    }

    // fbl + root directly into registers; issued now so they overlap the DMA.
    float fb[NJ];
#pragma unroll
    for (int j = 0; j < NJ; ++j) fb[j] = fbl[b * NJ + j];
    const float rx = root_position[b * 3 + 0] * 100.0f;
    const float ry = root_position[b * 3 + 1] * 100.0f;
    const float rz = root_position[b * 3 + 2] * 100.0f;

    __syncthreads();  // drains vmcnt before LDS reads

    float* srow = sq + lane * JF;

    M34 M0;
    {
        float4 q = *reinterpret_cast<const float4*>(&srow[0]);
        float Rr[9], Rt[3];
        make_RT(0, q, fb[0], soff, Rr, Rt);
#pragma unroll
        for (int i = 0; i < 9; ++i) M0.r[i] = Rr[i];
        M0.t[0] = Rt[0] + rx;
        M0.t[1] = Rt[1] + ry;
        M0.t[2] = Rt[2] + rz;
        *reinterpret_cast<float4*>(&srow[0]) =
            make_float4(M0.t[0], M0.t[1], M0.t[2], 1.0f);
    }

    // chains: 0→1..5, 0→6..10, 0→11..15 (save 13), 13→16..20, 13→21..25, 13→26..30
    M34 cur = M0;
#pragma unroll
    for (int j = 1; j <= 5; ++j) cur = step(cur, j, srow, fb, soff);
    cur = M0;
#pragma unroll
    for (int j = 6; j <= 10; ++j) cur = step(cur, j, srow, fb, soff);
    cur = M0;
    M34 M13;
#pragma unroll
    for (int j = 11; j <= 15; ++j) {
        cur = step(cur, j, srow, fb, soff);
        if (j == 13) M13 = cur;
    }
    cur = M13;
#pragma unroll
    for (int j = 16; j <= 20; ++j) cur = step(cur, j, srow, fb, soff);
    cur = M13;
#pragma unroll
    for (int j = 21; j <= 25; ++j) cur = step(cur, j, srow, fb, soff);
    cur = M13;
#pragma unroll
    for (int j = 26; j <= 30; ++j) cur = step(cur, j, srow, fb, soff);

    __syncthreads();  // LDS writes visible (single wave: cheap)

    // coalesced store of the whole tile: 31 x 1KB
    float4* gout = reinterpret_cast<float4*>(out + (size_t)rowBase * JF);
#pragma unroll
    for (int c = 0; c < NJ; ++c) {
        const int idx = c * RPB + lane;
        gout[idx] = *reinterpret_cast<const float4*>(&sq[idx * 4]);
    }
}

extern "C" void kernel_launch(void* const* d_in, const int* in_sizes, int n_in,
                              void* d_out, int out_size, void* d_ws, size_t ws_size,
                              hipStream_t stream) {
    const float* root = (const float*)d_in[0];
    const float* joint = (const float*)d_in[1];
    const float* fblp = (const float*)d_in[2];
    const float* offs = (const float*)d_in[3];
    float* out = (float*)d_out;

    const int B = in_sizes[0] / 3;  // 131072, multiple of RPB
    fk_layer_kernel<<<B / RPB, RPB, 0, stream>>>(root, joint, fblp, offs, out);
}

// Round 5
// 33.430 us; speedup vs baseline: 1.6107x; 1.3795x over previous
//
#include <hip/hip_runtime.h>

constexpr int NJ = 31;
constexpr int ROWS = 16;        // batch rows per block (64 threads, 4 lanes/row)
constexpr int JF = NJ * 4;      // 124 floats per row
constexpr int ROWB = JF * 4;    // 496 bytes per row
constexpr int QBYTES = ROWS * ROWB;    // 7936 B quat/out tile
constexpr int FBYTES = ROWS * NJ * 4;  // 1984 B fbl tile

struct M34 {
    float r[9];  // row-major 3x3
    float t[3];
};

// RT_j = R4(q) @ T_j as 3x4 affine; offsets read from global (L1-resident, 2KB).
__device__ __forceinline__ void make_RT(int j, float4 q, float len,
                                        const float* __restrict__ offs,
                                        float Rr[9], float Rt[3]) {
    const float w = q.x, x = q.y, y = q.z, z = q.w;
    const float two_s = 2.0f / (w * w + x * x + y * y + z * z);
    float R[9];
    R[0] = 1.0f - two_s * (y * y + z * z);
    R[1] = two_s * (x * y - z * w);
    R[2] = two_s * (x * z + y * w);
    R[3] = two_s * (x * y + z * w);
    R[4] = 1.0f - two_s * (x * x + z * z);
    R[5] = two_s * (y * z - x * w);
    R[6] = two_s * (x * z - y * w);
    R[7] = two_s * (y * z + x * w);
    R[8] = 1.0f - two_s * (x * x + y * y);

    const float4* O4 = reinterpret_cast<const float4*>(offs) + (size_t)j * 4;
    const float4 o0 = O4[0], o1 = O4[1], o2 = O4[2];  // rows 0..2 of 4x4
    const float O[12] = {o0.x, o0.y, o0.z, o1.x, o1.y, o1.z, o2.x, o2.y, o2.z,
                         o0.w * len, o1.w * len, o2.w * len};
#pragma unroll
    for (int r = 0; r < 3; ++r) {
#pragma unroll
        for (int c = 0; c < 3; ++c) {
            Rr[r * 3 + c] = R[r * 3 + 0] * O[0 + c] +
                            R[r * 3 + 1] * O[3 + c] +
                            R[r * 3 + 2] * O[6 + c];
        }
        Rt[r] = R[r * 3 + 0] * O[9] + R[r * 3 + 1] * O[10] + R[r * 3 + 2] * O[11];
    }
}

__device__ __forceinline__ M34 compose(const M34& P, const float Rr[9],
                                       const float Rt[3]) {
    M34 C;
#pragma unroll
    for (int r = 0; r < 3; ++r) {
#pragma unroll
        for (int c = 0; c < 3; ++c) {
            C.r[r * 3 + c] = P.r[r * 3 + 0] * Rr[0 * 3 + c] +
                             P.r[r * 3 + 1] * Rr[1 * 3 + c] +
                             P.r[r * 3 + 2] * Rr[2 * 3 + c];
        }
        C.t[r] = P.r[r * 3 + 0] * Rt[0] + P.r[r * 3 + 1] * Rt[1] +
                 P.r[r * 3 + 2] * Rt[2] + P.t[r];
    }
    return C;
}

__global__ __launch_bounds__(64, 4) void fk_layer_kernel(
    const float* __restrict__ root_position,  // (B,3)
    const float* __restrict__ joint,          // (B, NJ*4)
    const float* __restrict__ fbl,            // (B, NJ)
    const float* __restrict__ offsets,        // (NJ,4,4)
    float* __restrict__ out) {                // (B, NJ, 4)
    __shared__ float sq[QBYTES / 4 + 64];   // 7936 B + 256 B pad (clamped DMA tail)
    __shared__ float sfb[FBYTES / 4 + 16];  // 1984 B + 64 B pad

    const int lane = threadIdx.x;
    const int r = lane >> 2;      // row within tile
    const int c = lane & 3;       // chain lane
    const int rowBase = blockIdx.x * ROWS;

    // ---- stage quat tile: 8 x 1KB linear DMA, source clamped into region ----
    {
        const char* gbase = (const char*)(joint + (size_t)rowBase * JF);
#pragma unroll
        for (int ch = 0; ch < 8; ++ch) {
            int off = ch * 1024 + lane * 16;
            off = off > (QBYTES - 16) ? (QBYTES - 16) : off;  // pad dup, never read
            __builtin_amdgcn_global_load_lds(
                (const __attribute__((address_space(1))) unsigned int*)(gbase + off),
                (__attribute__((address_space(3))) unsigned int*)(sq + ch * 256),
                16, 0, 0);
        }
    }
    // ---- stage fbl tile: 2 x 1KB linear DMA, clamped ----
    {
        const char* fbase = (const char*)(fbl + (size_t)rowBase * NJ);
#pragma unroll
        for (int ch = 0; ch < 2; ++ch) {
            int off = ch * 1024 + lane * 16;
            off = off > (FBYTES - 16) ? (FBYTES - 16) : off;
            __builtin_amdgcn_global_load_lds(
                (const __attribute__((address_space(1))) unsigned int*)(fbase + off),
                (__attribute__((address_space(3))) unsigned int*)(sfb + ch * 256),
                16, 0, 0);
        }
    }

    // root for this lane's row (uniform within 4-lane group; overlaps DMA)
    const size_t brow = (size_t)(rowBase + r);
    const float rx = root_position[brow * 3 + 0] * 100.0f;
    const float ry = root_position[brow * 3 + 1] * 100.0f;
    const float rz = root_position[brow * 3 + 2] * 100.0f;

    __syncthreads();  // drain vmcnt (DMA + root) before LDS reads

    float* srow = sq + r * JF;
    const float* frow = sfb + r * NJ;

    // ---- M0 (all 4 lanes redundantly) ----
    M34 M0;
    {
        float4 q = *reinterpret_cast<const float4*>(&srow[0]);
        float Rr[9], Rt[3];
        make_RT(0, q, frow[0], offsets, Rr, Rt);
#pragma unroll
        for (int i = 0; i < 9; ++i) M0.r[i] = Rr[i];
        M0.t[0] = Rt[0] + rx;
        M0.t[1] = Rt[1] + ry;
        M0.t[2] = Rt[2] + rz;
        if (c == 0)
            *reinterpret_cast<float4*>(&srow[0]) =
                make_float4(M0.t[0], M0.t[1], M0.t[2], 1.0f);
    }

    const int cc = c < 2 ? c : 2;  // c==3 duplicates c==2 (stores masked)

    // ---- stage A: chains {1-5},{6-10},{11-15} from M0 ----
    M34 cur = M0, M13;
    {
        const int jb = 1 + 5 * cc;
#pragma unroll
        for (int s = 0; s < 5; ++s) {
            const int j = jb + s;
            float4 q = *reinterpret_cast<const float4*>(&srow[j * 4]);
            float Rr[9], Rt[3];
            make_RT(j, q, frow[j], offsets, Rr, Rt);
            cur = compose(cur, Rr, Rt);
            if (c < 3)
                *reinterpret_cast<float4*>(&srow[j * 4]) =
                    make_float4(cur.t[0], cur.t[1], cur.t[2], 1.0f);
            if (s == 2) M13 = cur;  // j==13 on the c==2/3 lanes
        }
    }

    // ---- broadcast M13 from lane (group|2) ----
    const int src = (lane & ~3) | 2;
#pragma unroll
    for (int i = 0; i < 9; ++i) M13.r[i] = __shfl(M13.r[i], src, 64);
#pragma unroll
    for (int i = 0; i < 3; ++i) M13.t[i] = __shfl(M13.t[i], src, 64);

    // ---- stage B: chains {16-20},{21-25},{26-30} from M13 ----
    cur = M13;
    {
        const int jb = 16 + 5 * cc;
#pragma unroll
        for (int s = 0; s < 5; ++s) {
            const int j = jb + s;
            float4 q = *reinterpret_cast<const float4*>(&srow[j * 4]);
            float Rr[9], Rt[3];
            make_RT(j, q, frow[j], offsets, Rr, Rt);
            cur = compose(cur, Rr, Rt);
            if (c < 3)
                *reinterpret_cast<float4*>(&srow[j * 4]) =
                    make_float4(cur.t[0], cur.t[1], cur.t[2], 1.0f);
        }
    }

    __syncthreads();  // LDS writes visible before tile store

    // ---- coalesced store: 496 float4 (7936 B contiguous) ----
    const float4* s4 = reinterpret_cast<const float4*>(sq);
    float4* gout = reinterpret_cast<float4*>(out + (size_t)rowBase * JF);
#pragma unroll
    for (int ch = 0; ch < 8; ++ch) {
        const int idx = ch * 64 + lane;
        if (idx < ROWS * NJ) gout[idx] = s4[idx];
    }
}

extern "C" void kernel_launch(void* const* d_in, const int* in_sizes, int n_in,
                              void* d_out, int out_size, void* d_ws, size_t ws_size,
                              hipStream_t stream) {
    const float* root = (const float*)d_in[0];
    const float* joint = (const float*)d_in[1];
    const float* fblp = (const float*)d_in[2];
    const float* offs = (const float*)d_in[3];
    float* out = (float*)d_out;

    const int B = in_sizes[0] / 3;  // 131072, multiple of ROWS
    fk_layer_kernel<<<B / ROWS, 64, 0, stream>>>(root, joint, fblp, offs, out);
}